// Round 14
// baseline (279.235 us; speedup 1.0000x reference)
//
#include <hip/hip_runtime.h>
#include <stdint.h>

#define NNODES 100000
#define NEDGES 100000
#define DIM    256
#define NCH    4          // 2 side + 2 rel
#define ET     64         // edges per tile
#define NT     1563       // ceil(NEDGES / ET)
#define NBX    64         // blocks per channel; each block strides tiles by NBX
#define RSF    264        // fp16 per staged row (256 + 8 pad -> conflict-benign)
#define CONVB  2048       // grid-stride conversion blocks

typedef _Float16 f16x8 __attribute__((ext_vector_type(8)));
typedef _Float16 f16x4 __attribute__((ext_vector_type(4)));
typedef float f32x4  __attribute__((ext_vector_type(4)));

// ---------------------------------------------------------------------------
// Fused prep: B tables (hi/lo fp16, MFMA B-fragment order) + h f32->fp16.
// Unchanged.
// ---------------------------------------------------------------------------
__global__ void prep_fused(const float* __restrict__ RW,
                           const float* __restrict__ dside,
                           const float* __restrict__ Wrel,
                           const float* __restrict__ h,
                           _Float16* __restrict__ Bh, _Float16* __restrict__ Bl,
                           _Float16* __restrict__ H16) {
    if (blockIdx.x < 128) {
        int t = blockIdx.x * blockDim.x + threadIdx.x;   // < 32768
        int lane = t & 63;
        int ft   = (t >> 6) & 15;
        int kc   = (t >> 10) & 7;
        int c    = t >> 13;
        int quad = lane >> 4, col = lane & 15;
        int f     = ft * 16 + col;
        int kbase = kc * 32 + quad * 8;

        f16x8 vh, vl;
#pragma unroll
        for (int j = 0; j < 8; ++j) {
            int k = kbase + j;
            float val;
            if (c < 2) {
                val = dside[c * DIM + f] * RW[f * DIM + k] * dside[c * DIM + k];
            } else {
                val = Wrel[(size_t)(c - 2) * DIM * DIM + f * DIM + k];
            }
            _Float16 hi = (_Float16)val;
            vh[j] = hi;
            vl[j] = (_Float16)(val - (float)hi);
        }
        ((f16x8*)Bh)[t] = vh;
        ((f16x8*)Bl)[t] = vl;
    } else {
        const int total4 = NNODES * DIM / 4;   // 6.4e6 f32x4 chunks
        const int stride = CONVB * 256;
        int i = (blockIdx.x - 128) * 256 + (int)threadIdx.x;
        const f32x4* s4 = (const f32x4*)h;
        f16x4* d4 = (f16x4*)H16;
        for (; i + stride < total4; i += 2 * stride) {
            f32x4 a = s4[i];
            f32x4 b = s4[i + stride];
            f16x4 oa, ob;
#pragma unroll
            for (int j = 0; j < 4; ++j) { oa[j] = (_Float16)a[j]; ob[j] = (_Float16)b[j]; }
            d4[i] = oa; d4[i + stride] = ob;
        }
        if (i < total4) {
            f32x4 a = s4[i];
            f16x4 o;
#pragma unroll
            for (int j = 0; j < 4; ++j) o[j] = (_Float16)a[j];
            d4[i] = o;
        }
    }
}

// ---------------------------------------------------------------------------
// Edge kernel v13 = v12 with the MFMA operands SWAPPED (compute C^T free):
//  A- and B-fragments of mfma_16x16x32_f16 share the same bit layout
//  (idx = lane&15, k = quad*8+j), so mfma(W_frag, R_frag, acc) computes
//  C^T[f,e] with zero extra cost. Lane then holds C[e=et*16+col][f=slice+
//  quad*4+r] -- the V values it needs in the epilogue are 4 CONTIGUOUS f16:
//    - 32 scalar ds_read_u16 (4-way conflicted) -> 8 ds_read_b64 (balanced)
//    - 64-op DPP tree -> 8 in-register FMAs + 2 __shfl_xor (16,32)
//  Everything else byte-identical to v12 (proven 118.9us): staging, K-loop
//  LDS reads, barriers, post-barrier gather issue, register schedule.
//  Predicted: SQ_LDS_BANK_CONFLICT 6.4M -> ~4M, dur ~108-113us.
// ---------------------------------------------------------------------------
__global__ __launch_bounds__(512, 1)
void edge_kernel(const _Float16* __restrict__ H16,
                 const int* __restrict__ src_idx,
                 const int* __restrict__ dst_idx,
                 const float* __restrict__ brel,
                 const _Float16* __restrict__ Bh_sw,
                 const _Float16* __restrict__ Bl_sw,
                 float* __restrict__ out) {
    const int c    = blockIdx.y;
    const int tid  = threadIdx.x;
    const int w    = tid >> 6;          // 0..7
    const int lane = tid & 63;
    const int quad = lane >> 4, col = lane & 15;

    __shared__ __align__(16) _Float16 s_a[ET * RSF];   // 33,792 B
    __shared__ __align__(16) _Float16 s_v[ET * RSF];   // 33,792 B
    __shared__ float red[8][ET];                       // 2 KB

    // ---- B registers: wave w holds ft = {2w, 2w+1}, all kc, hi+lo ----
    f16x8 Bh_r[8][2], Bl_r[8][2];
    {
        const f16x8* bh = (const f16x8*)Bh_sw;
        const f16x8* bl = (const f16x8*)Bl_sw;
#pragma unroll
        for (int kc = 0; kc < 8; ++kc)
#pragma unroll
            for (int ftl = 0; ftl < 2; ++ftl) {
                int o = ((c * 8 + kc) * 16 + (w * 2 + ftl)) * 64 + lane;
                Bh_r[kc][ftl] = bh[o];
                Bl_r[kc][ftl] = bl[o];
            }
    }
    // Pin B (B lives in AGPRs; pin keeps it there).
#pragma unroll
    for (int kc = 0; kc < 8; ++kc)
#pragma unroll
        for (int ftl = 0; ftl < 2; ++ftl)
            asm volatile("" : "+v"(Bh_r[kc][ftl]), "+v"(Bl_r[kc][ftl]));

    // Per-lane bias for the transposed C layout: f = (w*2+ftl)*16 + quad*4+r
    float b8[2][4];
#pragma unroll
    for (int ftl = 0; ftl < 2; ++ftl)
#pragma unroll
        for (int r = 0; r < 4; ++r) {
            int f = (w * 2 + ftl) * 16 + quad * 4 + r;
            b8[ftl][r] = (c >= 2) ? brel[(size_t)(c - 2) * DIM + f] : 0.f;
        }

    // Lane-packed index loads: lanes 0..7 -> src idx of rows w*8+0..7,
    // lanes 8..15 -> dst idx (pattern repeats harmlessly for lanes >= 16).
    const int  j8   = lane & 7;
    const bool isV  = (lane & 8) != 0;
    const int* ibase = (isV ? dst_idx : src_idx) + (size_t)c * NEDGES;

    auto loadpack = [&](int t) -> int {
        int e = t * ET + w * 8 + j8;
        if (e >= NEDGES) e = NEDGES - 1;
        return ibase[e];
    };

    // ---- Prologue: gather tile t0 rows; preload idx pack for t0+NBX ----
    const int t0 = blockIdx.x;
    f16x4 pA[8], pV[8];
    {
        int ip = loadpack(t0);
#pragma unroll
        for (int i = 0; i < 8; ++i) {
            int ia = __shfl(ip, i, 64);
            int iv = __shfl(ip, 8 + i, 64);
            pA[i] = *(const f16x4*)(H16 + (size_t)ia * DIM + lane * 4);
            pV[i] = *(const f16x4*)(H16 + (size_t)iv * DIM + lane * 4);
        }
    }
    int ipk0 = 0, ipk1 = 0;
    if (t0 + NBX < NT) ipk1 = loadpack(t0 + NBX);

    // ---- Tile body (ipkUse = idx for t+NBX, ipkLoad gets t+2*NBX) ----
    auto body = [&](int t, int& ipkUse, int& ipkLoad) {
        // stage tile t rows (gathered during previous tile)
#pragma unroll
        for (int i = 0; i < 8; ++i) {
            int lr = w * 8 + i;
            *(f16x4*)&s_a[lr * RSF + lane * 4] = pA[i];
            *(f16x4*)&s_v[lr * RSF + lane * 4] = pV[i];
        }

        __syncthreads();   // BARRIER1 (drains only the ds_writes above)

        // Issue idx loads 2 tiles ahead + row gathers 1 tile ahead; their
        // drain point is BARRIER2, covered by K-loop + epilogue (v12 win).
        if (t + 2 * NBX < NT) ipkLoad = loadpack(t + 2 * NBX);
        if (t + NBX < NT) {
#pragma unroll
            for (int i = 0; i < 8; ++i) {
                int ia = __shfl(ipkUse, i, 64);
                int iv = __shfl(ipkUse, 8 + i, 64);
                pA[i] = *(const f16x4*)(H16 + (size_t)ia * DIM + lane * 4);
                pV[i] = *(const f16x4*)(H16 + (size_t)iv * DIM + lane * 4);
            }
        }

        // K-loop: R (edge rows) from LDS as B-operand, W from AGPRs as
        // A-operand -> acc holds C^T. Same LDS reads as v12.
        f32x4 acc[4][2];   // [et][ftl]: C[e=et*16+col][f=(w*2+ftl)*16+quad*4+r]
#pragma unroll
        for (int et = 0; et < 4; ++et)
#pragma unroll
            for (int ftl = 0; ftl < 2; ++ftl) acc[et][ftl] = (f32x4){0.f, 0.f, 0.f, 0.f};

#pragma unroll
        for (int kc = 0; kc < 8; ++kc) {
            f16x8 R[4];
#pragma unroll
            for (int et = 0; et < 4; ++et)
                R[et] = *(const f16x8*)&s_a[(et * 16 + col) * RSF + kc * 32 + quad * 8];
#pragma unroll
            for (int ftl = 0; ftl < 2; ++ftl) {
#pragma unroll
                for (int et = 0; et < 4; ++et)
                    acc[et][ftl] = __builtin_amdgcn_mfma_f32_16x16x32_f16(Bh_r[kc][ftl], R[et], acc[et][ftl], 0, 0, 0);
#pragma unroll
                for (int et = 0; et < 4; ++et)
                    acc[et][ftl] = __builtin_amdgcn_mfma_f32_16x16x32_f16(Bl_r[kc][ftl], R[et], acc[et][ftl], 0, 0, 0);
            }
        }

        // Epilogue (transposed layout): lane's V values are contiguous.
        // p = sum over this lane's 8 f-values; then reduce across quads
        // (lanes +-16/+-32) and finally across waves via red[].
#pragma unroll
        for (int et = 0; et < 4; ++et) {
            float p = 0.f;
#pragma unroll
            for (int ftl = 0; ftl < 2; ++ftl) {
                f16x4 v4 = *(const f16x4*)&s_v[(et * 16 + col) * RSF + (w * 2 + ftl) * 16 + quad * 4];
#pragma unroll
                for (int r = 0; r < 4; ++r)
                    p += (acc[et][ftl][r] + b8[ftl][r]) * (float)v4[r];
            }
            p += __shfl_xor(p, 16, 64);
            p += __shfl_xor(p, 32, 64);
            if (quad == 0) red[w][et * 16 + col] = p;
        }

        __syncthreads();   // BARRIER2: red ready (gathers drain here, covered)

        if (tid < ET) {
            int e = t * ET + tid;
            if (e < NEDGES) {
                float s = 0.f;
#pragma unroll
                for (int i = 0; i < 8; ++i) s += red[i][tid];
                out[(size_t)c * NEDGES + e] = s;
            }
        }
        // red write-after-read across tiles ordered by next BARRIER1.
    };

    int t = t0;
    while (true) {
        body(t, ipk1, ipk0);            // parity 0: use t+NBX idx from ipk1
        t += NBX; if (t >= NT) break;
        body(t, ipk0, ipk1);            // parity 1
        t += NBX; if (t >= NT) break;
    }
}

extern "C" void kernel_launch(void* const* d_in, const int* in_sizes, int n_in,
                              void* d_out, int out_size, void* d_ws, size_t ws_size,
                              hipStream_t stream) {
    const float* hmat  = (const float*)d_in[0];
    const int*   src   = (const int*)d_in[1];
    const int*   dst   = (const int*)d_in[2];
    const float* RW    = (const float*)d_in[3];
    const float* dside = (const float*)d_in[4];
    const float* Wrel  = (const float*)d_in[5];
    const float* brel  = (const float*)d_in[6];
    float* out = (float*)d_out;

    // Workspace: Bh (512 KB) | Bl (512 KB) | H16 (51.2 MB)
    const size_t nB = (size_t)NCH * DIM * DIM;   // fp16 per table
    _Float16* Bh  = (_Float16*)d_ws;
    _Float16* Bl  = Bh + nB;
    _Float16* H16 = Bl + nB;

    prep_fused<<<dim3(128 + CONVB), dim3(256), 0, stream>>>(
        RW, dside, Wrel, hmat, Bh, Bl, H16);

    dim3 grid(NBX, NCH);
    edge_kernel<<<grid, dim3(512), 0, stream>>>(H16, src, dst, brel, Bh, Bl, out);
}